// Round 7
// baseline (319.477 us; speedup 1.0000x reference)
//
#include <hip/hip_runtime.h>
#include <math.h>

// LiquidEchoHead: persistent-block pipelined version.
//
// Evidence through round 6: best fused kernel = 99 us @ 2.7 TB/s, VALUBusy 18%,
// VGPR 36 (compiler sank the upfront load batch). True HBM traffic is only
// 256 MB (mem_r/mem_i are L3-resident zeros, FETCH shows x only) -> 41 us
// floor. Single-row blocks have a tiny issue duty cycle: ~21 VMEM ops then a
// ~2000-cycle dependent sincos/reduce/barrier window with nothing outstanding.
// Harness fill kernel: 6.9 TB/s at 3 waves/CU -> continuous issue is all that
// matters.
//
// Fix: each block owns 4 rows (grid = B/4), fully unrolled, 2-deep pipeline:
//   iter k: issue x-loads(row k+1) + mem-loads(row k)  [pinned: sched_barrier]
//           compute row k (its x was issued one full iteration ago)
// Row-invariant params (1/(1+|wq|), bq, 1/(1+|wo|), 2bo) are computed once
// per block and live in registers. Cross-wave reduce uses 4 distinct LDS
// slots + raw s_barrier with lgkmcnt-only wait (vmcnt prefetch survives).
//
// Identity: cos(a)cos(b)-sin(a)sin(b)=cos(a+b); cos(a)sin(b)+sin(a)cos(b)=sin(a+b)
// -> phase 2 needs one sincos on (theta_r + theta_i).

#define PHI_F 1.61803398874989f

typedef float f32x4 __attribute__((ext_vector_type(4)));

struct RowX { f32x4 xr0, xr1, xi0, xi1; };
struct RowM { f32x4 mr0, mr1, mi0, mi1; };
struct Params { f32x4 iq0, iq1, bq0, bq1, io0, io1, tb0, tb1; };

__device__ __forceinline__ RowX load_x(const f32x4* __restrict__ xr4,
                                       const f32x4* __restrict__ xi4,
                                       size_t base, int c0, int c1) {
    RowX s;
    s.xr0 = __builtin_nontemporal_load(&xr4[base + c0]);   // read-once streams
    s.xr1 = __builtin_nontemporal_load(&xr4[base + c1]);
    s.xi0 = __builtin_nontemporal_load(&xi4[base + c0]);
    s.xi1 = __builtin_nontemporal_load(&xi4[base + c1]);
    return s;
}

__device__ __forceinline__ RowM load_m(const f32x4* __restrict__ mr4,
                                       const f32x4* __restrict__ mi4,
                                       size_t base, int c0, int c1) {
    RowM s;
    s.mr0 = mr4[base + c0];                                // L3-resident
    s.mr1 = mr4[base + c1];
    s.mi0 = mi4[base + c0];
    s.mi1 = mi4[base + c1];
    return s;
}

__device__ __forceinline__ void process_row(
    const RowX& x, const RowM& m, float tv, int slot, int tid,
    const Params& P, float inv_scale,
    f32x4* __restrict__ or4, f32x4* __restrict__ oi4,
    size_t base, int c0, int c1, float2 (*sRI)[4])
{
    // ---- Phase 1: per-thread interference partials. ----
    float accR = 0.f, accI = 0.f;
    #pragma unroll
    for (int j = 0; j < 4; ++j) {
        float xrv = x.xr0[j], xiv = x.xi0[j];
        float th  = fmaf(xrv, P.iq0[j], P.bq0[j]);
        float sq, cq;
        __sincosf(th, &sq, &cq);
        accR = fmaf(cq, xrv, fmaf(sq, xiv, accR));
        accI = fmaf(cq, xiv, fmaf(-sq, xrv, accI));
    }
    #pragma unroll
    for (int j = 0; j < 4; ++j) {
        float xrv = x.xr1[j], xiv = x.xi1[j];
        float th  = fmaf(xrv, P.iq1[j], P.bq1[j]);
        float sq, cq;
        __sincosf(th, &sq, &cq);
        accR = fmaf(cq, xrv, fmaf(sq, xiv, accR));
        accI = fmaf(cq, xiv, fmaf(-sq, xrv, accI));
    }
    // ---- Wave butterfly, cross-wave via private LDS slot + raw barrier. ----
    #pragma unroll
    for (int off = 32; off > 0; off >>= 1) {
        accR += __shfl_xor(accR, off);
        accI += __shfl_xor(accI, off);
    }
    const int wave = tid >> 6;
    if ((tid & 63) == 0) sRI[slot][wave] = make_float2(accR, accI);
    asm volatile("s_waitcnt lgkmcnt(0)" ::: "memory");   // LDS only; vmcnt prefetch survives
    __builtin_amdgcn_s_barrier();
    __builtin_amdgcn_sched_barrier(0);                   // pin: no hoist above barrier
    float2 q0 = sRI[slot][0], q1 = sRI[slot][1], q2 = sRI[slot][2], q3 = sRI[slot][3];

    // All threads compute alpha redundantly (single barrier per row).
    float ir = (q0.x + q1.x) + (q2.x + q3.x);
    float ii = (q0.y + q1.y) + (q2.y + q3.y);
    float interf = sqrtf(fmaf(ir, ir, ii * ii));
    float z     = fmaf(interf, inv_scale, -2.0f);
    float sig   = 1.f / (1.f + __expf(-z));   // sigmoid(z)
    float alpha = __expf(sig - 1.f);          // exp(-k*(1-sig)), k=1
    float beta  = 1.f - alpha;
    float tphi2 = 2.0f * PHI_F * tv;

    // ---- Phase 2: oscillator evolution + nontemporal stores. ----
    f32x4 oR, oI;
    #pragma unroll
    for (int j = 0; j < 4; ++j) {
        float br = fmaf(alpha, x.xr0[j], beta * m.mr0[j]);
        float bi = fmaf(alpha, x.xi0[j], beta * m.mi0[j]);
        float ang = fmaf(br + bi, P.io0[j], P.tb0[j] + tphi2);
        float sv, cv;
        __sincosf(ang, &sv, &cv);
        oR[j] = cv;   // evolved_real = cos(theta_r + theta_i)
        oI[j] = sv;   // evolved_imag = sin(theta_r + theta_i)
    }
    __builtin_nontemporal_store(oR, &or4[base + c0]);
    __builtin_nontemporal_store(oI, &oi4[base + c0]);
    #pragma unroll
    for (int j = 0; j < 4; ++j) {
        float br = fmaf(alpha, x.xr1[j], beta * m.mr1[j]);
        float bi = fmaf(alpha, x.xi1[j], beta * m.mi1[j]);
        float ang = fmaf(br + bi, P.io1[j], P.tb1[j] + tphi2);
        float sv, cv;
        __sincosf(ang, &sv, &cv);
        oR[j] = cv;
        oI[j] = sv;
    }
    __builtin_nontemporal_store(oR, &or4[base + c1]);
    __builtin_nontemporal_store(oI, &oi4[base + c1]);
}

// Persistent fast path: D==2048, grid = B/4, rows r0 + k*rstride.
__global__ __launch_bounds__(256) void liquid_echo_persist(
    const float* __restrict__ x_real, const float* __restrict__ x_imag,
    const float* __restrict__ t_arr,
    const float* __restrict__ w_query, const float* __restrict__ b_query,
    const float* __restrict__ w_osc,   const float* __restrict__ b_osc,
    const float* __restrict__ mem_r,   const float* __restrict__ mem_i,
    float* __restrict__ out_r, float* __restrict__ out_i,
    int rstride, float inv_scale)
{
    const int tid = (int)threadIdx.x;
    const int c0 = tid, c1 = tid + 256;

    const f32x4* xr4 = (const f32x4*)x_real;
    const f32x4* xi4 = (const f32x4*)x_imag;
    const f32x4* mr4 = (const f32x4*)mem_r;
    const f32x4* mi4 = (const f32x4*)mem_i;
    const f32x4* wq4 = (const f32x4*)w_query;
    const f32x4* bq4 = (const f32x4*)b_query;
    const f32x4* wo4 = (const f32x4*)w_osc;
    const f32x4* bo4 = (const f32x4*)b_osc;
    f32x4* or4 = (f32x4*)out_r;
    f32x4* oi4 = (f32x4*)out_i;

    __shared__ float2 sRI[4][4];   // [row-slot][wave] -- no reuse, no WAR

    const int r0 = (int)blockIdx.x;
    const int r1 = r0 + rstride, r2 = r1 + rstride, r3 = r2 + rstride;
    const size_t b0 = (size_t)r0 << 9, b1 = (size_t)r1 << 9;
    const size_t b2 = (size_t)r2 << 9, b3 = (size_t)r3 << 9;

    // ---- Row-invariant params: load + transform ONCE, hold in registers. ----
    f32x4 wq0 = wq4[c0], wq1 = wq4[c1], bqa = bq4[c0], bqb = bq4[c1];
    f32x4 wo0 = wo4[c0], wo1 = wo4[c1], boa = bo4[c0], bob = bo4[c1];
    Params P;
    #pragma unroll
    for (int j = 0; j < 4; ++j) {
        P.iq0[j] = __builtin_amdgcn_rcpf(1.f + fabsf(wq0[j]));
        P.iq1[j] = __builtin_amdgcn_rcpf(1.f + fabsf(wq1[j]));
        P.io0[j] = __builtin_amdgcn_rcpf(1.f + fabsf(wo0[j]));
        P.io1[j] = __builtin_amdgcn_rcpf(1.f + fabsf(wo1[j]));
        P.bq0[j] = bqa[j];
        P.bq1[j] = bqb[j];
        P.tb0[j] = 2.f * boa[j];
        P.tb1[j] = 2.f * bob[j];
    }

    // ---- Prologue: row0's x in flight. ----
    RowX xa = load_x(xr4, xi4, b0, c0, c1);
    float t0 = t_arr[r0];

    // ---- iter 0: prefetch row1 x + row0 mem, compute row0. ----
    RowM m0 = load_m(mr4, mi4, b0, c0, c1);
    RowX xb = load_x(xr4, xi4, b1, c0, c1);
    float t1 = t_arr[r1];
    __builtin_amdgcn_sched_barrier(0);     // pin issue point
    process_row(xa, m0, t0, 0, tid, P, inv_scale, or4, oi4, b0, c0, c1, sRI);

    // ---- iter 1 ----
    RowM m1 = load_m(mr4, mi4, b1, c0, c1);
    RowX xc = load_x(xr4, xi4, b2, c0, c1);
    float t2 = t_arr[r2];
    __builtin_amdgcn_sched_barrier(0);
    process_row(xb, m1, t1, 1, tid, P, inv_scale, or4, oi4, b1, c0, c1, sRI);

    // ---- iter 2 ----
    RowM m2 = load_m(mr4, mi4, b2, c0, c1);
    RowX xd = load_x(xr4, xi4, b3, c0, c1);
    float t3 = t_arr[r3];
    __builtin_amdgcn_sched_barrier(0);
    process_row(xc, m2, t2, 2, tid, P, inv_scale, or4, oi4, b2, c0, c1, sRI);

    // ---- iter 3 (no prefetch) ----
    RowM m3 = load_m(mr4, mi4, b3, c0, c1);
    __builtin_amdgcn_sched_barrier(0);
    process_row(xd, m3, t3, 3, tid, P, inv_scale, or4, oi4, b3, c0, c1, sRI);
}

// ---- Generic fallback (any D multiple of 4): round-0 structure. ----
__global__ __launch_bounds__(256) void liquid_echo_gen(
    const float* __restrict__ x_real, const float* __restrict__ x_imag,
    const float* __restrict__ t_arr,
    const float* __restrict__ w_query, const float* __restrict__ b_query,
    const float* __restrict__ w_osc,   const float* __restrict__ b_osc,
    const float* __restrict__ mem_r,   const float* __restrict__ mem_i,
    float* __restrict__ out_r, float* __restrict__ out_i,
    int D, float inv_scale)
{
    const int row = blockIdx.x;
    const int d4  = D >> 2;
    const size_t base4 = (size_t)row * d4;

    const float4* xr4 = (const float4*)x_real + base4;
    const float4* xi4 = (const float4*)x_imag + base4;
    const float4* wq4 = (const float4*)w_query;
    const float4* bq4 = (const float4*)b_query;

    float accR = 0.f, accI = 0.f;
    for (int c = (int)threadIdx.x; c < d4; c += 256) {
        float4 xr = xr4[c];
        float4 xi = xi4[c];
        float4 wq = wq4[c];
        float4 bq = bq4[c];
        #pragma unroll
        for (int j = 0; j < 4; ++j) {
            float xrv = (&xr.x)[j];
            float xiv = (&xi.x)[j];
            float wl  = 1.f + fabsf((&wq.x)[j]);
            float th  = xrv * __builtin_amdgcn_rcpf(wl) + (&bq.x)[j];
            float sq, cq;
            __sincosf(th, &sq, &cq);
            accR = fmaf(cq, xrv, fmaf(sq, xiv, accR));
            accI = fmaf(cq, xiv, fmaf(-sq, xrv, accI));
        }
    }
    #pragma unroll
    for (int off = 32; off > 0; off >>= 1) {
        accR += __shfl_xor(accR, off);
        accI += __shfl_xor(accI, off);
    }
    __shared__ float sR[4], sI[4];
    __shared__ float sAlpha;
    const int wave = (int)threadIdx.x >> 6;
    if ((threadIdx.x & 63) == 0) { sR[wave] = accR; sI[wave] = accI; }
    __syncthreads();
    if (threadIdx.x == 0) {
        float ir = sR[0] + sR[1] + sR[2] + sR[3];
        float ii = sI[0] + sI[1] + sI[2] + sI[3];
        float interf = sqrtf(fmaf(ir, ir, ii * ii));
        float z = fmaf(interf, inv_scale, -2.0f);
        float sig = 1.f / (1.f + __expf(-z));
        sAlpha = __expf(sig - 1.f);
    }
    __syncthreads();

    const float alpha = sAlpha;
    const float beta  = 1.f - alpha;
    const float tphi2 = 2.0f * PHI_F * t_arr[row];

    const float4* wo4 = (const float4*)w_osc;
    const float4* bo4 = (const float4*)b_osc;
    const float4* mr4 = (const float4*)mem_r + base4;
    const float4* mi4 = (const float4*)mem_i + base4;
    float4* or4 = (float4*)out_r + base4;
    float4* oi4 = (float4*)out_i + base4;

    for (int c = (int)threadIdx.x; c < d4; c += 256) {
        float4 xr = xr4[c];
        float4 xi = xi4[c];
        float4 wo = wo4[c];
        float4 bo = bo4[c];
        float4 mr = mr4[c];
        float4 mi = mi4[c];
        float4 oR, oI;
        #pragma unroll
        for (int j = 0; j < 4; ++j) {
            float br = fmaf(alpha, (&xr.x)[j], beta * (&mr.x)[j]);
            float bi = fmaf(alpha, (&xi.x)[j], beta * (&mi.x)[j]);
            float wl = 1.f + fabsf((&wo.x)[j]);
            float ang = fmaf(br + bi, __builtin_amdgcn_rcpf(wl),
                             fmaf(2.f, (&bo.x)[j], tphi2));
            float sv, cv;
            __sincosf(ang, &sv, &cv);
            (&oR.x)[j] = cv;
            (&oI.x)[j] = sv;
        }
        or4[c] = oR;
        oi4[c] = oI;
    }
}

extern "C" void kernel_launch(void* const* d_in, const int* in_sizes, int n_in,
                              void* d_out, int out_size, void* d_ws, size_t ws_size,
                              hipStream_t stream) {
    const float* x_real   = (const float*)d_in[0];
    const float* x_imag   = (const float*)d_in[1];
    const float* t_arr    = (const float*)d_in[2];
    const float* w_query  = (const float*)d_in[3];
    const float* b_query  = (const float*)d_in[4];
    const float* w_osc    = (const float*)d_in[5];
    const float* b_osc    = (const float*)d_in[6];
    const float* mem_r    = (const float*)d_in[7];
    const float* mem_i    = (const float*)d_in[8];

    const int B = in_sizes[2];   // t is [B]
    const int D = in_sizes[3];   // w_query is [D]

    float* out_r = (float*)d_out;
    float* out_i = out_r + (size_t)B * D;

    const float inv_scale = 1.0f / sqrtf((float)D);

    if (D == 2048 && (B & 3) == 0 && B >= 4) {
        const int rstride = B >> 2;            // grid = B/4, 4 rows/block
        liquid_echo_persist<<<rstride, 256, 0, stream>>>(
            x_real, x_imag, t_arr, w_query, b_query, w_osc, b_osc,
            mem_r, mem_i, out_r, out_i, rstride, inv_scale);
    } else {
        liquid_echo_gen<<<B, 256, 0, stream>>>(
            x_real, x_imag, t_arr, w_query, b_query, w_osc, b_osc,
            mem_r, mem_i, out_r, out_i, D, inv_scale);
    }
}